// Round 1
// baseline (282.464 us; speedup 1.0000x reference)
//
#include <hip/hip_runtime.h>
#include <math.h>

#define B_   64
#define C_   64
#define D_   512
#define O_   256
#define NREG 8
#define G_   8
#define M_   (B_ * C_)   // 4096 rows

// ---------------- rid: channel -> region id ----------------
__global__ void rid_kernel(const int* __restrict__ region_indices, int* __restrict__ rid) {
    int t = threadIdx.x;           // 0..63 == NREG*G_
    int r = t / G_;
    int ch = region_indices[t];
    rid[ch] = r;
}

// ---------------- fp32 tiled GEMM, 64x64 tile, 4x4/thread ----------------
// EPI 0: C = A*B                      (a / bpart)
// EPI 1: C = 0.5*leaky(A*B+bias) + 0.5*resid   (x1)
// EPI 2: C = leaky(A*B+bias)          (out)
template<int EPI>
__global__ __launch_bounds__(256)
void gemm_kernel(const float* __restrict__ A, const float* __restrict__ Bm,
                 float* __restrict__ Co, int M, int N, int K,
                 const float* __restrict__ bias, const float* __restrict__ resid)
{
    __shared__ float As[16][65];   // [k][row]
    __shared__ float Bs[16][64];   // [k][col]
    const int tid = threadIdx.x;
    const int tx = tid & 15, ty = tid >> 4;
    const int mtile = blockIdx.y * 64, ntile = blockIdx.x * 64;

    float acc[4][4] = {};

    for (int kt = 0; kt < K; kt += 16) {
        // A tile: 64 rows x 16 k  (1024 elems, 4/thread)
        {
            int c = tid & 15, r0 = tid >> 4;
            #pragma unroll
            for (int rr = 0; rr < 4; rr++) {
                int r = r0 + rr * 16;
                As[c][r] = A[(size_t)(mtile + r) * K + kt + c];
            }
        }
        // B tile: 16 k x 64 cols
        {
            int n = tid & 63, c0 = tid >> 6;
            #pragma unroll
            for (int cc = 0; cc < 4; cc++) {
                int c = c0 + cc * 4;
                Bs[c][n] = Bm[(size_t)(kt + c) * N + ntile + n];
            }
        }
        __syncthreads();
        #pragma unroll
        for (int kk = 0; kk < 16; kk++) {
            float av[4], bv[4];
            #pragma unroll
            for (int i = 0; i < 4; i++) av[i] = As[kk][ty * 4 + i];
            #pragma unroll
            for (int j = 0; j < 4; j++) bv[j] = Bs[kk][tx * 4 + j];
            #pragma unroll
            for (int i = 0; i < 4; i++)
                #pragma unroll
                for (int j = 0; j < 4; j++)
                    acc[i][j] += av[i] * bv[j];
        }
        __syncthreads();
    }

    #pragma unroll
    for (int i = 0; i < 4; i++) {
        int row = mtile + ty * 4 + i;
        #pragma unroll
        for (int j = 0; j < 4; j++) {
            int col = ntile + tx * 4 + j;
            float v = acc[i][j];
            if (EPI >= 1) v += bias[col];
            if (EPI == 1) {
                v = (v >= 0.f) ? v : 0.2f * v;
                v = 0.5f * v + 0.5f * resid[(size_t)row * N + col];
            }
            if (EPI == 2) {
                v = (v >= 0.f) ? v : 0.2f * v;
            }
            Co[(size_t)row * N + col] = v;
        }
    }
}

// ---------------- scores + softmax + m1 (one wave per (b,i)) ----------------
__global__ __launch_bounds__(64)
void scores_m1_kernel(const float* __restrict__ a, const float* __restrict__ bpart,
                      const float* __restrict__ x,
                      const float* __restrict__ b1, const float* __restrict__ W2,
                      const float* __restrict__ b2,
                      const int* __restrict__ region_indices, const int* __restrict__ rid,
                      float* __restrict__ adjw, float* __restrict__ m1)
{
    const int lane = threadIdx.x;          // 0..63
    const int bi = blockIdx.x;             // b*C + i
    const int b = bi / C_, i = bi % C_;
    const int r = rid[i];

    int members[G_];
    #pragma unroll
    for (int m = 0; m < G_; m++) members[m] = region_indices[r * G_ + m];

    const int d0 = lane * 8;
    float ai[8], w2v[8];
    const float* arow = a + (size_t)bi * D_ + d0;
    #pragma unroll
    for (int t = 0; t < 8; t++) { ai[t] = arow[t] + b1[d0 + t]; w2v[t] = W2[d0 + t]; }

    const float bias2 = b2[0];
    float sc[G_];
    float scmax = -INFINITY;
    for (int m = 0; m < G_; m++) {
        int j = members[m];
        if (j == i) { sc[m] = -INFINITY; continue; }
        const float* brow = bpart + ((size_t)(b * C_ + j)) * D_ + d0;
        float p = 0.f;
        #pragma unroll
        for (int t = 0; t < 8; t++) {
            float h = ai[t] + brow[t];
            h = (h > 0.f) ? h : 0.f;
            p += h * w2v[t];
        }
        #pragma unroll
        for (int off = 32; off >= 1; off >>= 1) p += __shfl_xor(p, off);
        sc[m] = p + bias2;
        scmax = fmaxf(scmax, sc[m]);
    }

    float esum = 0.f, w[G_];
    for (int m = 0; m < G_; m++) {
        if (sc[m] == -INFINITY) { w[m] = 0.f; continue; }
        w[m] = expf(sc[m] - scmax);
        esum += w[m];
    }
    const float inv = 1.f / esum;

    float accv[8] = {};
    for (int m = 0; m < G_; m++) {
        w[m] *= inv;
        if (w[m] == 0.f) continue;
        int j = members[m];
        const float* xrow = x + ((size_t)(b * C_ + j)) * D_ + d0;
        #pragma unroll
        for (int t = 0; t < 8; t++) accv[t] += w[m] * xrow[t];
    }
    float* m1row = m1 + (size_t)bi * D_ + d0;
    #pragma unroll
    for (int t = 0; t < 8; t++) m1row[t] = accv[t];

    if (lane < G_) adjw[(size_t)bi * G_ + lane] = w[lane];
}

// ---------------- m2 = adj @ x1 (sparse) ----------------
__global__ __launch_bounds__(64)
void m2_kernel(const float* __restrict__ x1,
               const int* __restrict__ region_indices, const int* __restrict__ rid,
               const float* __restrict__ adjw, float* __restrict__ m2)
{
    const int lane = threadIdx.x;
    const int bi = blockIdx.x;
    const int b = bi / C_, i = bi % C_;
    const int r = rid[i];
    const int d0 = lane * 8;

    float accv[8] = {};
    for (int m = 0; m < G_; m++) {
        float wm = adjw[(size_t)bi * G_ + m];
        if (wm == 0.f) continue;
        int j = region_indices[r * G_ + m];
        const float* row = x1 + ((size_t)(b * C_ + j)) * D_ + d0;
        #pragma unroll
        for (int t = 0; t < 8; t++) accv[t] += wm * row[t];
    }
    float* orow = m2 + (size_t)bi * D_ + d0;
    #pragma unroll
    for (int t = 0; t < 8; t++) orow[t] = accv[t];
}

// ---------------- launch ----------------
extern "C" void kernel_launch(void* const* d_in, const int* in_sizes, int n_in,
                              void* d_out, int out_size, void* d_ws, size_t ws_size,
                              hipStream_t stream) {
    const float* x    = (const float*)d_in[0];
    const float* W1   = (const float*)d_in[1];
    const float* b1   = (const float*)d_in[2];
    const float* W2   = (const float*)d_in[3];
    const float* b2   = (const float*)d_in[4];
    const float* Wg1  = (const float*)d_in[5];
    const float* bg1  = (const float*)d_in[6];
    const float* Wg2  = (const float*)d_in[7];
    const float* bg2  = (const float*)d_in[8];
    const int* region_indices = (const int*)d_in[9];
    float* out = (float*)d_out;

    const size_t plane = (size_t)M_ * D_;   // 2M floats = 8 MB
    char* ws = (char*)d_ws;
    float* a    = (float*)ws;                       // plane 0
    float* bp   = (float*)(ws + plane * 4);         // plane 1
    float* m1   = (float*)(ws + plane * 8);         // plane 2
    float* x1   = bp;                               // reuse (bpart dead after scores)
    float* m2   = a;                                // reuse (a dead after scores)
    float* adjw = (float*)(ws + plane * 12);        // M_*8 floats
    int*   rid  = (int*)(ws + plane * 12 + (size_t)M_ * G_ * 4);

    rid_kernel<<<1, 64, 0, stream>>>(region_indices, rid);

    // a = x @ W1[:D], bpart = x @ W1[D:]
    gemm_kernel<0><<<dim3(8, 64), 256, 0, stream>>>(x, W1,             a,  M_, D_, D_, nullptr, nullptr);
    gemm_kernel<0><<<dim3(8, 64), 256, 0, stream>>>(x, W1 + D_ * D_,   bp, M_, D_, D_, nullptr, nullptr);

    scores_m1_kernel<<<M_, 64, 0, stream>>>(a, bp, x, b1, W2, b2, region_indices, rid, adjw, m1);

    // x1 = 0.5*leaky(m1@Wg1+bg1) + 0.5*x
    gemm_kernel<1><<<dim3(8, 64), 256, 0, stream>>>(m1, Wg1, x1, M_, D_, D_, bg1, x);

    m2_kernel<<<M_, 64, 0, stream>>>(x1, region_indices, rid, adjw, m2);

    // out = leaky(m2@Wg2+bg2)
    gemm_kernel<2><<<dim3(4, 64), 256, 0, stream>>>(m2, Wg2, out, M_, O_, D_, bg2, nullptr);
}

// Round 2
// 137.858 us; speedup vs baseline: 2.0490x; 2.0490x over previous
//
#include <hip/hip_runtime.h>
#include <math.h>

#define B_   64
#define C_   64
#define D_   512
#define O_   256
#define NREG 8
#define G_   8
#define M_   (B_ * C_)   // 4096 rows

typedef __attribute__((ext_vector_type(8))) short s16x8;
typedef __attribute__((ext_vector_type(4))) float f32x4;
typedef unsigned short u16;
typedef unsigned int   u32;

__device__ __forceinline__ float bf2f(u16 u) {
    u32 v = ((u32)u) << 16;
    return __uint_as_float(v);
}
__device__ __forceinline__ u16 f2bf(float f) {
    u32 u = __float_as_uint(f);
    u32 r = (u + 0x7FFFu + ((u >> 16) & 1u)) >> 16;
    return (u16)r;
}

// ---------------- rid: channel -> region id ----------------
__global__ void rid_kernel(const int* __restrict__ region_indices, int* __restrict__ rid) {
    int t = threadIdx.x;           // 0..63
    int r = t / G_;
    int ch = region_indices[t];
    rid[ch] = r;
}

// ---------------- x (fp32) -> bf16 ----------------
__global__ __launch_bounds__(256) void f32_to_bf16_vec(const float* __restrict__ in,
                                                       u16* __restrict__ out, int n8) {
    int i = blockIdx.x * blockDim.x + threadIdx.x;
    if (i >= n8) return;
    const float4* p = (const float4*)(in + (size_t)i * 8);
    float4 v0 = p[0], v1 = p[1];
    s16x8 o;
    o[0] = (short)f2bf(v0.x); o[1] = (short)f2bf(v0.y);
    o[2] = (short)f2bf(v0.z); o[3] = (short)f2bf(v0.w);
    o[4] = (short)f2bf(v1.x); o[5] = (short)f2bf(v1.y);
    o[6] = (short)f2bf(v1.z); o[7] = (short)f2bf(v1.w);
    *(s16x8*)(out + (size_t)i * 8) = o;
}

// ---------------- transpose fp32 W[K][N] -> bf16 Wt[N][K] ----------------
__global__ __launch_bounds__(256) void transpose_to_bf16(const float* __restrict__ W,
                                                         u16* __restrict__ Wt, int K, int N) {
    __shared__ float tile[32][33];
    int n0 = blockIdx.x * 32, k0 = blockIdx.y * 32;
    int tx = threadIdx.x, ty = threadIdx.y;   // (32, 8)
    #pragma unroll
    for (int j = 0; j < 4; j++)
        tile[ty + j * 8][tx] = W[(size_t)(k0 + ty + j * 8) * N + n0 + tx];
    __syncthreads();
    #pragma unroll
    for (int j = 0; j < 4; j++)
        Wt[(size_t)(n0 + ty + j * 8) * K + k0 + tx] = f2bf(tile[tx][ty + j * 8]);
}

// ---------------- bf16 MFMA GEMM ----------------
// A [M x 512] bf16 row-major (lda=512). Bt = B^T [N x ldbt] bf16.
// EPI 0: dual bf16 out (a | bpart) selected by k-offset half
// EPI 1: x1 = bf16(0.5*leaky(acc+bias) + 0.5*resid)
// EPI 2: out = leaky(acc+bias), fp32
#define LDP 40   // padded LDS row length (elems): 80B rows -> <=2-way bank conflict, 16B aligned

template<int BM, int BN, int EPI>
__global__ __launch_bounds__(256)
void mfma_gemm(const u16* __restrict__ A, const u16* __restrict__ Bt, int ldbt,
               u16* __restrict__ Cbf0, u16* __restrict__ Cbf1,
               const float* __restrict__ bias, const float* __restrict__ resid,
               float* __restrict__ Cf)
{
    constexpr int K   = 512;
    constexpr int MR  = BM / 32;             // frags per wave in M
    constexpr int NR  = BN / 32;             // frags per wave in N
    constexpr int CHA = (BM * 32) / (256 * 8);
    constexpr int CHB = (BN * 32) / (256 * 8);
    constexpr int NBH = 512 / BN;            // N-blocks per 512 cols (EPI0)

    __shared__ __align__(16) u16 As[BM][LDP];
    __shared__ __align__(16) u16 Bs[BN][LDP];

    const int tid  = threadIdx.x;
    const int lane = tid & 63, w = tid >> 6;
    const int wr = w >> 1, wc = w & 1;
    const int lr = lane & 15, lq = lane >> 4;

    const int bx = blockIdx.x, by = blockIdx.y;
    const int m0 = by * BM;
    int nbase, koff;
    if (EPI == 0) { nbase = (bx % NBH) * BN; koff = (bx / NBH) * 512; }
    else          { nbase = bx * BN;         koff = 0; }

    const int ar = tid >> 2;          // staging row (0..63)
    const int ac = (tid & 3) * 8;     // staging col

    f32x4 acc[MR][NR] = {};
    s16x8 stA[CHA], stB[CHB];

    auto loadG = [&](int kt) {
        #pragma unroll
        for (int ch = 0; ch < CHA; ch++)
            stA[ch] = *(const s16x8*)(A + (size_t)(m0 + ar + ch * 64) * K + kt + ac);
        #pragma unroll
        for (int ch = 0; ch < CHB; ch++)
            stB[ch] = *(const s16x8*)(Bt + (size_t)(nbase + ar + ch * 64) * ldbt + koff + kt + ac);
    };

    loadG(0);
    for (int kt = 0; kt < K; kt += 32) {
        __syncthreads();
        #pragma unroll
        for (int ch = 0; ch < CHA; ch++)
            *(s16x8*)(&As[ar + ch * 64][ac]) = stA[ch];
        #pragma unroll
        for (int ch = 0; ch < CHB; ch++)
            *(s16x8*)(&Bs[ar + ch * 64][ac]) = stB[ch];
        __syncthreads();
        if (kt + 32 < K) loadG(kt + 32);   // prefetch overlaps MFMA below

        s16x8 af[MR], bfr[NR];
        #pragma unroll
        for (int m = 0; m < MR; m++)
            af[m] = *(const s16x8*)(&As[wr * (BM / 2) + m * 16 + lr][lq * 8]);
        #pragma unroll
        for (int n = 0; n < NR; n++)
            bfr[n] = *(const s16x8*)(&Bs[wc * (BN / 2) + n * 16 + lr][lq * 8]);
        #pragma unroll
        for (int m = 0; m < MR; m++)
            #pragma unroll
            for (int n = 0; n < NR; n++)
                acc[m][n] = __builtin_amdgcn_mfma_f32_16x16x32_bf16(af[m], bfr[n], acc[m][n], 0, 0, 0);
    }

    #pragma unroll
    for (int m = 0; m < MR; m++) {
        #pragma unroll
        for (int n = 0; n < NR; n++) {
            #pragma unroll
            for (int j = 0; j < 4; j++) {
                int row = m0 + wr * (BM / 2) + m * 16 + lq * 4 + j;
                int col = nbase + wc * (BN / 2) + n * 16 + lr;
                float v = acc[m][n][j];
                if (EPI == 0) {
                    u16* dst = koff ? Cbf1 : Cbf0;
                    dst[(size_t)row * 512 + col] = f2bf(v);
                } else if (EPI == 1) {
                    v += bias[col];
                    v = (v >= 0.f) ? v : 0.2f * v;
                    v = 0.5f * v + 0.5f * resid[(size_t)row * 512 + col];
                    Cbf0[(size_t)row * 512 + col] = f2bf(v);
                } else {
                    v += bias[col];
                    v = (v >= 0.f) ? v : 0.2f * v;
                    Cf[(size_t)row * 256 + col] = v;
                }
            }
        }
    }
}

// ---------------- scores + softmax + m1 (one wave per (b,i)) ----------------
__global__ __launch_bounds__(64)
void scores_m1_kernel(const u16* __restrict__ a, const u16* __restrict__ bpart,
                      const float* __restrict__ x,
                      const float* __restrict__ b1, const float* __restrict__ W2,
                      const float* __restrict__ b2,
                      const int* __restrict__ region_indices, const int* __restrict__ rid,
                      float* __restrict__ adjw, u16* __restrict__ m1)
{
    const int lane = threadIdx.x;          // 0..63
    const int bi = blockIdx.x;             // b*C + i
    const int b = bi / C_, i = bi % C_;
    const int r = rid[i];

    int members[G_];
    #pragma unroll
    for (int m = 0; m < G_; m++) members[m] = region_indices[r * G_ + m];

    const int d0 = lane * 8;
    float ai[8], w2v[8];
    s16x8 av8 = *(const s16x8*)(a + (size_t)bi * D_ + d0);
    const float4* b1v = (const float4*)(b1 + d0);
    const float4* w2p = (const float4*)(W2 + d0);
    float4 b1a = b1v[0], b1b = b1v[1];
    float4 w2a = w2p[0], w2b = w2p[1];
    ai[0] = bf2f((u16)av8[0]) + b1a.x; ai[1] = bf2f((u16)av8[1]) + b1a.y;
    ai[2] = bf2f((u16)av8[2]) + b1a.z; ai[3] = bf2f((u16)av8[3]) + b1a.w;
    ai[4] = bf2f((u16)av8[4]) + b1b.x; ai[5] = bf2f((u16)av8[5]) + b1b.y;
    ai[6] = bf2f((u16)av8[6]) + b1b.z; ai[7] = bf2f((u16)av8[7]) + b1b.w;
    w2v[0] = w2a.x; w2v[1] = w2a.y; w2v[2] = w2a.z; w2v[3] = w2a.w;
    w2v[4] = w2b.x; w2v[5] = w2b.y; w2v[6] = w2b.z; w2v[7] = w2b.w;

    const float bias2 = b2[0];
    float sc[G_];
    float scmax = -INFINITY;
    for (int m = 0; m < G_; m++) {
        int j = members[m];
        if (j == i) { sc[m] = -INFINITY; continue; }
        s16x8 bv8 = *(const s16x8*)(bpart + ((size_t)(b * C_ + j)) * D_ + d0);
        float p = 0.f;
        #pragma unroll
        for (int t = 0; t < 8; t++) {
            float h = ai[t] + bf2f((u16)bv8[t]);
            h = (h > 0.f) ? h : 0.f;
            p += h * w2v[t];
        }
        #pragma unroll
        for (int off = 32; off >= 1; off >>= 1) p += __shfl_xor(p, off);
        sc[m] = p + bias2;
        scmax = fmaxf(scmax, sc[m]);
    }

    float esum = 0.f, wgt[G_];
    for (int m = 0; m < G_; m++) {
        if (sc[m] == -INFINITY) { wgt[m] = 0.f; continue; }
        wgt[m] = expf(sc[m] - scmax);
        esum += wgt[m];
    }
    const float inv = 1.f / esum;

    float accv[8] = {};
    for (int m = 0; m < G_; m++) {
        wgt[m] *= inv;
        if (wgt[m] == 0.f) continue;
        int j = members[m];
        const float4* xp = (const float4*)(x + ((size_t)(b * C_ + j)) * D_ + d0);
        float4 xa = xp[0], xb = xp[1];
        accv[0] += wgt[m] * xa.x; accv[1] += wgt[m] * xa.y;
        accv[2] += wgt[m] * xa.z; accv[3] += wgt[m] * xa.w;
        accv[4] += wgt[m] * xb.x; accv[5] += wgt[m] * xb.y;
        accv[6] += wgt[m] * xb.z; accv[7] += wgt[m] * xb.w;
    }
    s16x8 o;
    #pragma unroll
    for (int t = 0; t < 8; t++) o[t] = (short)f2bf(accv[t]);
    *(s16x8*)(m1 + (size_t)bi * D_ + d0) = o;

    if (lane < G_) adjw[(size_t)bi * G_ + lane] = wgt[lane];
}

// ---------------- m2 = adj @ x1 (sparse, bf16 in/out) ----------------
__global__ __launch_bounds__(64)
void m2_kernel(const u16* __restrict__ x1,
               const int* __restrict__ region_indices, const int* __restrict__ rid,
               const float* __restrict__ adjw, u16* __restrict__ m2)
{
    const int lane = threadIdx.x;
    const int bi = blockIdx.x;
    const int b = bi / C_, i = bi % C_;
    const int r = rid[i];
    const int d0 = lane * 8;

    float accv[8] = {};
    for (int m = 0; m < G_; m++) {
        float wm = adjw[(size_t)bi * G_ + m];
        if (wm == 0.f) continue;
        int j = region_indices[r * G_ + m];
        s16x8 v = *(const s16x8*)(x1 + ((size_t)(b * C_ + j)) * D_ + d0);
        #pragma unroll
        for (int t = 0; t < 8; t++) accv[t] += wm * bf2f((u16)v[t]);
    }
    s16x8 o;
    #pragma unroll
    for (int t = 0; t < 8; t++) o[t] = (short)f2bf(accv[t]);
    *(s16x8*)(m2 + (size_t)bi * D_ + d0) = o;
}

// ---------------- launch ----------------
extern "C" void kernel_launch(void* const* d_in, const int* in_sizes, int n_in,
                              void* d_out, int out_size, void* d_ws, size_t ws_size,
                              hipStream_t stream) {
    const float* x    = (const float*)d_in[0];
    const float* W1   = (const float*)d_in[1];
    const float* b1   = (const float*)d_in[2];
    const float* W2   = (const float*)d_in[3];
    const float* b2   = (const float*)d_in[4];
    const float* Wg1  = (const float*)d_in[5];
    const float* bg1  = (const float*)d_in[6];
    const float* Wg2  = (const float*)d_in[7];
    const float* bg2  = (const float*)d_in[8];
    const int* region_indices = (const int*)d_in[9];
    float* out = (float*)d_out;

    char* ws = (char*)d_ws;
    const size_t MB = 1024 * 1024;
    u16*   x_bf  = (u16*)(ws);                       // 4 MB
    u16*   W1t   = (u16*)(ws + 4 * MB);              // 1 MB   [512][1024]
    u16*   Wg1t  = (u16*)(ws + 5 * MB);              // 0.5 MB [512][512]
    u16*   Wg2t  = (u16*)(ws + 5 * MB + 512 * 1024); // 0.25MB [256][512]
    u16*   a_bf  = (u16*)(ws + 6 * MB);              // 4 MB
    u16*   bp_bf = (u16*)(ws + 10 * MB);             // 4 MB
    u16*   m1_bf = (u16*)(ws + 14 * MB);             // 4 MB
    u16*   x1_bf = a_bf;                             // reuse (a dead after scores)
    u16*   m2_bf = bp_bf;                            // reuse (bp dead after scores)
    float* adjw  = (float*)(ws + 18 * MB);           // 128 KB
    int*   rid   = (int*)(ws + 18 * MB + 256 * 1024);

    rid_kernel<<<1, 64, 0, stream>>>(region_indices, rid);
    f32_to_bf16_vec<<<(M_ * D_ / 8 + 255) / 256, 256, 0, stream>>>(x, x_bf, M_ * D_ / 8);
    transpose_to_bf16<<<dim3(512 / 32, 1024 / 32), dim3(32, 8), 0, stream>>>(W1,  W1t,  1024, 512);
    transpose_to_bf16<<<dim3(512 / 32, 512 / 32),  dim3(32, 8), 0, stream>>>(Wg1, Wg1t, 512,  512);
    transpose_to_bf16<<<dim3(256 / 32, 512 / 32),  dim3(32, 8), 0, stream>>>(Wg2, Wg2t, 512,  256);

    // a | bpart = x @ W1 (both halves), bf16 out.  grid: 16 x 32 = 512 WGs
    mfma_gemm<128, 64, 0><<<dim3(16, 32), 256, 0, stream>>>(
        x_bf, W1t, 1024, a_bf, bp_bf, nullptr, nullptr, nullptr);

    scores_m1_kernel<<<M_, 64, 0, stream>>>(a_bf, bp_bf, x, b1, W2, b2,
                                            region_indices, rid, adjw, m1_bf);

    // x1 = bf16(0.5*leaky(m1@Wg1+bg1) + 0.5*x).  grid: 8 x 64 = 512 WGs
    mfma_gemm<64, 64, 1><<<dim3(8, 64), 256, 0, stream>>>(
        m1_bf, Wg1t, 512, x1_bf, nullptr, bg1, x, nullptr);

    m2_kernel<<<M_, 64, 0, stream>>>(x1_bf, region_indices, rid, adjw, m2_bf);

    // out = leaky(m2@Wg2+bg2), fp32.  grid: 4 x 64 = 256 WGs
    mfma_gemm<64, 64, 2><<<dim3(4, 64), 256, 0, stream>>>(
        m2_bf, Wg2t, 512, nullptr, nullptr, bg2, nullptr, out);
}

// Round 3
// 120.505 us; speedup vs baseline: 2.3440x; 1.1440x over previous
//
#include <hip/hip_runtime.h>
#include <math.h>

#define B_   64
#define C_   64
#define D_   512
#define O_   256
#define G_   8
#define M_   4096

typedef __attribute__((ext_vector_type(8))) short s16x8;
typedef __attribute__((ext_vector_type(4))) float f32x4;
typedef unsigned short u16;
typedef unsigned int   u32;

__device__ __forceinline__ float bf2f(u16 u) { return __uint_as_float(((u32)u) << 16); }
__device__ __forceinline__ u16 f2bf(float f) {
    u32 u = __float_as_uint(f);
    return (u16)((u + 0x7FFFu + ((u >> 16) & 1u)) >> 16);
}
__device__ __forceinline__ void gload16(const void* g, void* l) {
    __builtin_amdgcn_global_load_lds((const __attribute__((address_space(1))) u32*)g,
                                     (__attribute__((address_space(3))) u32*)l, 16, 0, 0);
}

// ---------------- prep: x->bf16, W transposes->bf16 B^T, rid ----------------
// blocks [0,1024): x cvt | [1024,1536): W1 (2 halves) | [1536,1792): Wg1
// [1792,1920): Wg2 | 1920: rid
__global__ __launch_bounds__(256)
void prep_kernel(const float* __restrict__ x, u16* __restrict__ x_bf,
                 const float* __restrict__ W1, u16* __restrict__ W1t,
                 const float* __restrict__ Wg1, u16* __restrict__ Wg1t,
                 const float* __restrict__ Wg2, u16* __restrict__ Wg2t,
                 const int* __restrict__ region_indices, int* __restrict__ rid)
{
    __shared__ float tile[32][33];
    const int bx = blockIdx.x, tid = threadIdx.x;
    if (bx < 1024) {                       // x -> bf16 (2M elems, 8/thread)
        size_t i = ((size_t)bx * 256 + tid) * 8;
        const float4* p = (const float4*)(x + i);
        float4 v0 = p[0], v1 = p[1];
        s16x8 o;
        o[0] = (short)f2bf(v0.x); o[1] = (short)f2bf(v0.y);
        o[2] = (short)f2bf(v0.z); o[3] = (short)f2bf(v0.w);
        o[4] = (short)f2bf(v1.x); o[5] = (short)f2bf(v1.y);
        o[6] = (short)f2bf(v1.z); o[7] = (short)f2bf(v1.w);
        *(s16x8*)(x_bf + i) = o;
        return;
    }
    if (bx >= 1920) {                      // rid
        if (tid < 64) rid[region_indices[tid]] = tid >> 3;
        return;
    }
    const float* src; u16* dst; int k0, n0, nsrc, obase;
    if (bx < 1536) {                       // W1 half h: [512x512] -> W1t rows [h*512..)
        int idx = bx - 1024, h = idx >> 8, t = idx & 255;
        int tn = t & 15, tk = t >> 4;
        src = W1 + (size_t)h * 512 * 512; dst = W1t; obase = h * 512;
        k0 = tk * 32; n0 = tn * 32; nsrc = 512;
    } else if (bx < 1792) {                // Wg1 [512x512]
        int t = bx - 1536, tn = t & 15, tk = t >> 4;
        src = Wg1; dst = Wg1t; obase = 0;
        k0 = tk * 32; n0 = tn * 32; nsrc = 512;
    } else {                               // Wg2 [512x256]
        int t = bx - 1792, tn = t & 7, tk = t >> 3;
        src = Wg2; dst = Wg2t; obase = 0;
        k0 = tk * 32; n0 = tn * 32; nsrc = 256;
    }
    int tx = tid & 31, ty = tid >> 5;
    #pragma unroll
    for (int j = 0; j < 4; j++)
        tile[ty + j * 8][tx] = src[(size_t)(k0 + ty + j * 8) * nsrc + n0 + tx];
    __syncthreads();
    #pragma unroll
    for (int j = 0; j < 4; j++)
        dst[(size_t)(obase + n0 + ty + j * 8) * 512 + k0 + tx] = f2bf(tile[tx][ty + j * 8]);
}

// ---------------- bf16 MFMA GEMM: gload_lds + XOR-swizzle + 2-phase dbuf ----
// A [M x 512] bf16. Bt = B^T [N x 512] bf16. K=512, BK=64.
// EPI 0: bf16 out split at col 512 (a | bpart)
// EPI 1: bf16(0.5*leaky(acc+bias) + 0.5*resid)
// EPI 2: fp32 leaky(acc+bias)
template<int BM, int BN, int EPI>
__global__ __launch_bounds__(256)
void mfma_gemm(const u16* __restrict__ A, const u16* __restrict__ Bt,
               u16* __restrict__ Obf0, u16* __restrict__ Obf1,
               const float* __restrict__ bias, const float* __restrict__ resid,
               float* __restrict__ Of)
{
    constexpr int K = 512, BK = 64, NT = K / BK;
    constexpr int MR = BM / 32, NR = BN / 32;   // frags per wave (wave = BM/2 x BN/2)
    constexpr int CA = BM / 32, CB = BN / 32;   // stage issues (32 rows each)

    __shared__ __align__(16) u16 As[2][BM * BK];
    __shared__ __align__(16) u16 Bs[2][BN * BK];

    const int tid = threadIdx.x;
    const int lane = tid & 63;
    const int w = tid >> 6, wr = w >> 1, wc = w & 1;
    const int lr = lane & 15, lq = lane >> 4;
    const int m0 = blockIdx.y * BM, n0 = blockIdx.x * BN;

    const int sr  = tid >> 3;            // staging row within 32-row chunk
    const int ss  = tid & 7;             // LDS slot (16B units)
    const int gsl = ss ^ (sr & 7);       // pre-swizzled source slot (involution)

    f32x4 acc[MR][NR] = {};

    auto stage = [&](int buf, int kt) {
        #pragma unroll
        for (int ch = 0; ch < CA; ch++)
            gload16(A + (size_t)(m0 + ch * 32 + sr) * K + kt + gsl * 8,
                    &As[buf][ch * 2048 + tid * 8]);
        #pragma unroll
        for (int ch = 0; ch < CB; ch++)
            gload16(Bt + (size_t)(n0 + ch * 32 + sr) * K + kt + gsl * 8,
                    &Bs[buf][ch * 2048 + tid * 8]);
    };

    stage(0, 0);
    int cur = 0;
    for (int t = 0; t < NT; t++) {
        __syncthreads();                          // drains vmcnt -> buf[cur] ready
        if (t + 1 < NT) stage(cur ^ 1, (t + 1) * BK);
        const u16* as = As[cur]; const u16* bs = Bs[cur];
        #pragma unroll
        for (int ks = 0; ks < 2; ks++) {
            s16x8 af[MR], bfv[NR];
            #pragma unroll
            for (int m = 0; m < MR; m++) {
                int r = wr * (BM / 2) + m * 16 + lr;
                af[m] = *(const s16x8*)(as + r * 64 + (((ks * 4 + lq) ^ (r & 7)) * 8));
            }
            #pragma unroll
            for (int n = 0; n < NR; n++) {
                int r = wc * (BN / 2) + n * 16 + lr;
                bfv[n] = *(const s16x8*)(bs + r * 64 + (((ks * 4 + lq) ^ (r & 7)) * 8));
            }
            #pragma unroll
            for (int m = 0; m < MR; m++)
                #pragma unroll
                for (int n = 0; n < NR; n++)
                    acc[m][n] = __builtin_amdgcn_mfma_f32_16x16x32_bf16(af[m], bfv[n], acc[m][n], 0, 0, 0);
        }
        cur ^= 1;
    }

    #pragma unroll
    for (int m = 0; m < MR; m++) {
        #pragma unroll
        for (int n = 0; n < NR; n++) {
            #pragma unroll
            for (int j = 0; j < 4; j++) {
                int row = m0 + wr * (BM / 2) + m * 16 + lq * 4 + j;
                int col = n0 + wc * (BN / 2) + n * 16 + lr;
                float v = acc[m][n][j];
                if (EPI == 0) {
                    if (col < 512) Obf0[(size_t)row * 512 + col] = f2bf(v);
                    else           Obf1[(size_t)row * 512 + col - 512] = f2bf(v);
                } else if (EPI == 1) {
                    v += bias[col];
                    v = (v >= 0.f) ? v : 0.2f * v;
                    v = 0.5f * v + 0.5f * resid[(size_t)row * 512 + col];
                    Obf0[(size_t)row * 512 + col] = f2bf(v);
                } else {
                    v += bias[col];
                    v = (v >= 0.f) ? v : 0.2f * v;
                    Of[(size_t)row * 256 + col] = v;
                }
            }
        }
    }
}

// ---------------- scores + softmax + m1: 4 waves/block, batched reduce ------
__global__ __launch_bounds__(256)
void scores_m1_kernel(const u16* __restrict__ a, const u16* __restrict__ bpart,
                      const float* __restrict__ x,
                      const float* __restrict__ b1, const float* __restrict__ W2,
                      const float* __restrict__ b2,
                      const int* __restrict__ region_indices, const int* __restrict__ rid,
                      float* __restrict__ adjw, u16* __restrict__ m1)
{
    const int lane = threadIdx.x & 63;
    const int bi = blockIdx.x * 4 + (threadIdx.x >> 6);
    const int b = bi >> 6, i = bi & 63;
    const int r = rid[i];
    int members[8];
    #pragma unroll
    for (int m = 0; m < 8; m++) members[m] = region_indices[r * 8 + m];

    const int d0 = lane * 8;
    s16x8 av8 = *(const s16x8*)(a + (size_t)bi * 512 + d0);
    float4 b1a = *(const float4*)(b1 + d0), b1b = *(const float4*)(b1 + d0 + 4);
    float4 w2a = *(const float4*)(W2 + d0), w2b = *(const float4*)(W2 + d0 + 4);
    float ai[8] = { bf2f((u16)av8[0]) + b1a.x, bf2f((u16)av8[1]) + b1a.y,
                    bf2f((u16)av8[2]) + b1a.z, bf2f((u16)av8[3]) + b1a.w,
                    bf2f((u16)av8[4]) + b1b.x, bf2f((u16)av8[5]) + b1b.y,
                    bf2f((u16)av8[6]) + b1b.z, bf2f((u16)av8[7]) + b1b.w };
    float w2v[8] = { w2a.x, w2a.y, w2a.z, w2a.w, w2b.x, w2b.y, w2b.z, w2b.w };

    s16x8 bv[8];                              // all member rows issued up-front
    #pragma unroll
    for (int m = 0; m < 8; m++)
        bv[m] = *(const s16x8*)(bpart + ((size_t)(b * 64 + members[m])) * 512 + d0);

    float p[8];
    #pragma unroll
    for (int m = 0; m < 8; m++) {
        float s = 0.f;
        #pragma unroll
        for (int t = 0; t < 8; t++) {
            float h = ai[t] + bf2f((u16)bv[m][t]);
            s += fmaxf(h, 0.f) * w2v[t];
        }
        p[m] = s;
    }
    #pragma unroll
    for (int off = 32; off >= 1; off >>= 1)   // 6 steps, 8 values each
        #pragma unroll
        for (int m = 0; m < 8; m++) p[m] += __shfl_xor(p[m], off);

    const float bias2 = b2[0];
    float scmax = -INFINITY;
    #pragma unroll
    for (int m = 0; m < 8; m++) {
        p[m] = (members[m] == i) ? -INFINITY : p[m] + bias2;
        scmax = fmaxf(scmax, p[m]);
    }
    float esum = 0.f;
    #pragma unroll
    for (int m = 0; m < 8; m++) {
        p[m] = (members[m] == i) ? 0.f : __expf(p[m] - scmax);
        esum += p[m];
    }
    const float inv = 1.f / esum;

    float accv[8] = {};
    #pragma unroll
    for (int m = 0; m < 8; m++) {
        p[m] *= inv;
        if (members[m] != i) {
            const float4* xp = (const float4*)(x + ((size_t)(b * 64 + members[m])) * 512 + d0);
            float4 xa = xp[0], xb = xp[1];
            accv[0] += p[m] * xa.x; accv[1] += p[m] * xa.y;
            accv[2] += p[m] * xa.z; accv[3] += p[m] * xa.w;
            accv[4] += p[m] * xb.x; accv[5] += p[m] * xb.y;
            accv[6] += p[m] * xb.z; accv[7] += p[m] * xb.w;
        }
    }
    s16x8 o;
    #pragma unroll
    for (int t = 0; t < 8; t++) o[t] = (short)f2bf(accv[t]);
    *(s16x8*)(m1 + (size_t)bi * 512 + d0) = o;
    if (lane < 8) adjw[(size_t)bi * 8 + lane] = p[lane];
}

// ---------------- m2 = adj @ x1 (sparse): 4 waves/block ----------------
__global__ __launch_bounds__(256)
void m2_kernel(const u16* __restrict__ x1,
               const int* __restrict__ region_indices, const int* __restrict__ rid,
               const float* __restrict__ adjw, u16* __restrict__ m2)
{
    const int lane = threadIdx.x & 63;
    const int bi = blockIdx.x * 4 + (threadIdx.x >> 6);
    const int b = bi >> 6, i = bi & 63;
    const int r = rid[i];
    const int d0 = lane * 8;
    float accv[8] = {};
    #pragma unroll
    for (int m = 0; m < 8; m++) {
        float wm = adjw[(size_t)bi * 8 + m];
        int j = region_indices[r * 8 + m];
        s16x8 v = *(const s16x8*)(x1 + ((size_t)(b * 64 + j)) * 512 + d0);
        #pragma unroll
        for (int t = 0; t < 8; t++) accv[t] += wm * bf2f((u16)v[t]);
    }
    s16x8 o;
    #pragma unroll
    for (int t = 0; t < 8; t++) o[t] = (short)f2bf(accv[t]);
    *(s16x8*)(m2 + (size_t)bi * 512 + d0) = o;
}

// ---------------- launch ----------------
extern "C" void kernel_launch(void* const* d_in, const int* in_sizes, int n_in,
                              void* d_out, int out_size, void* d_ws, size_t ws_size,
                              hipStream_t stream) {
    const float* x    = (const float*)d_in[0];
    const float* W1   = (const float*)d_in[1];
    const float* b1   = (const float*)d_in[2];
    const float* W2   = (const float*)d_in[3];
    const float* b2   = (const float*)d_in[4];
    const float* Wg1  = (const float*)d_in[5];
    const float* bg1  = (const float*)d_in[6];
    const float* Wg2  = (const float*)d_in[7];
    const float* bg2  = (const float*)d_in[8];
    const int* region_indices = (const int*)d_in[9];
    float* out = (float*)d_out;

    char* ws = (char*)d_ws;
    const size_t MB = 1024 * 1024;
    u16*   x_bf  = (u16*)(ws);                        // 4 MB
    u16*   W1t   = (u16*)(ws + 4 * MB);               // 1 MB   [1024][512]
    u16*   Wg1t  = (u16*)(ws + 5 * MB);               // 0.5 MB [512][512]
    u16*   Wg2t  = (u16*)(ws + 5 * MB + 512 * 1024);  // 0.25MB [256][512]
    u16*   a_bf  = (u16*)(ws + 6 * MB);               // 4 MB
    u16*   bp_bf = (u16*)(ws + 10 * MB);              // 4 MB
    u16*   m1_bf = (u16*)(ws + 14 * MB);              // 4 MB
    u16*   x1_bf = a_bf;                              // reuse
    u16*   m2_bf = bp_bf;                             // reuse
    float* adjw  = (float*)(ws + 18 * MB);            // 128 KB
    int*   rid   = (int*)(ws + 18 * MB + 256 * 1024);

    prep_kernel<<<1921, 256, 0, stream>>>(x, x_bf, W1, W1t, Wg1, Wg1t, Wg2, Wg2t,
                                          region_indices, rid);

    // a | bp = x @ [W1a|W1b]  (M=4096, N=1024, K=512)
    mfma_gemm<128, 64, 0><<<dim3(16, 32), 256, 0, stream>>>(
        x_bf, W1t, a_bf, bp_bf, nullptr, nullptr, nullptr);

    scores_m1_kernel<<<1024, 256, 0, stream>>>(a_bf, bp_bf, x, b1, W2, b2,
                                               region_indices, rid, adjw, m1_bf);

    // x1 = bf16(0.5*leaky(m1@Wg1+bg1) + 0.5*x)  (N=512)
    mfma_gemm<64, 64, 1><<<dim3(8, 64), 256, 0, stream>>>(
        m1_bf, Wg1t, x1_bf, nullptr, bg1, x, nullptr);

    m2_kernel<<<1024, 256, 0, stream>>>(x1_bf, region_indices, rid, adjw, m2_bf);

    // out = leaky(m2@Wg2+bg2)  (N=256, fp32)
    mfma_gemm<64, 64, 2><<<dim3(4, 64), 256, 0, stream>>>(
        m2_bf, Wg2t, nullptr, nullptr, bg2, nullptr, out);
}

// Round 4
// 120.280 us; speedup vs baseline: 2.3484x; 1.0019x over previous
//
#include <hip/hip_runtime.h>
#include <math.h>

#define B_   64
#define C_   64
#define D_   512
#define O_   256
#define G_   8
#define M_   4096

typedef __attribute__((ext_vector_type(8))) short s16x8;
typedef __attribute__((ext_vector_type(4))) float f32x4;
typedef unsigned short u16;
typedef unsigned int   u32;

__device__ __forceinline__ float bf2f(u16 u) { return __uint_as_float(((u32)u) << 16); }
__device__ __forceinline__ u16 f2bf(float f) {
    u32 u = __float_as_uint(f);
    return (u16)((u + 0x7FFFu + ((u >> 16) & 1u)) >> 16);
}
__device__ __forceinline__ void gload16(const void* g, void* l) {
    __builtin_amdgcn_global_load_lds((const __attribute__((address_space(1))) u32*)g,
                                     (__attribute__((address_space(3))) u32*)l, 16, 0, 0);
}
// bijective XCD swizzle (m204): nwg must be a multiple of 8; nx a power of 2
__device__ __forceinline__ void xcd_swz(int& bx, int& by) {
    int nx = (int)gridDim.x;
    int L = bx + by * nx;
    int nwg = nx * (int)gridDim.y;
    int nid = (L & 7) * (nwg >> 3) + (L >> 3);
    bx = nid & (nx - 1);
    by = nid / nx;
}

// ---------------- prep: x->bf16, W transposes -> bf16 B^T ----------------
// blocks [0,1024): x cvt | [1024,1536): W1 | [1536,1792): Wg1 | [1792,1920): Wg2
__global__ __launch_bounds__(256)
void prep_kernel(const float* __restrict__ x, u16* __restrict__ x_bf,
                 const float* __restrict__ W1, u16* __restrict__ W1t,
                 const float* __restrict__ Wg1, u16* __restrict__ Wg1t,
                 const float* __restrict__ Wg2, u16* __restrict__ Wg2t)
{
    __shared__ float tile[32][33];
    const int bx = blockIdx.x, tid = threadIdx.x;
    if (bx < 1024) {
        size_t i = ((size_t)bx * 256 + tid) * 8;
        const float4* p = (const float4*)(x + i);
        float4 v0 = p[0], v1 = p[1];
        s16x8 o;
        o[0] = (short)f2bf(v0.x); o[1] = (short)f2bf(v0.y);
        o[2] = (short)f2bf(v0.z); o[3] = (short)f2bf(v0.w);
        o[4] = (short)f2bf(v1.x); o[5] = (short)f2bf(v1.y);
        o[6] = (short)f2bf(v1.z); o[7] = (short)f2bf(v1.w);
        *(s16x8*)(x_bf + i) = o;
        return;
    }
    const float* src; u16* dst; int k0, n0, nsrc, obase;
    if (bx < 1536) {                       // W1 half h: [512x512] -> W1t rows [h*512..)
        int idx = bx - 1024, h = idx >> 8, t = idx & 255;
        src = W1 + (size_t)h * 512 * 512; dst = W1t; obase = h * 512;
        k0 = (t >> 4) * 32; n0 = (t & 15) * 32; nsrc = 512;
    } else if (bx < 1792) {                // Wg1 [512x512]
        int t = bx - 1536;
        src = Wg1; dst = Wg1t; obase = 0;
        k0 = (t >> 4) * 32; n0 = (t & 15) * 32; nsrc = 512;
    } else {                               // Wg2 [512x256]
        int t = bx - 1792;
        src = Wg2; dst = Wg2t; obase = 0;
        k0 = (t >> 3) * 32; n0 = (t & 7) * 32; nsrc = 256;
    }
    int tx = tid & 31, ty = tid >> 5;
    #pragma unroll
    for (int j = 0; j < 4; j++)
        tile[ty + j * 8][tx] = src[(size_t)(k0 + ty + j * 8) * nsrc + n0 + tx];
    __syncthreads();
    #pragma unroll
    for (int j = 0; j < 4; j++)
        dst[(size_t)(obase + n0 + ty + j * 8) * 512 + k0 + tx] = f2bf(tile[tx][ty + j * 8]);
}

// ---------------- bf16 MFMA GEMM: gload_lds + XOR-swizzle + 2-phase dbuf ----
// EPI 0: bf16 out split at col 512 (a | bpart).  EPI 2: fp32 leaky(acc+bias).
template<int BM, int BN, int EPI>
__global__ __launch_bounds__(256)
void mfma_gemm(const u16* __restrict__ A, const u16* __restrict__ Bt,
               u16* __restrict__ Obf0, u16* __restrict__ Obf1,
               const float* __restrict__ bias, float* __restrict__ Of)
{
    constexpr int K = 512, BK = 64, NT = K / BK;
    constexpr int MR = BM / 32, NR = BN / 32;
    constexpr int CA = BM / 32, CB = BN / 32;

    __shared__ __align__(16) u16 As[2][BM * BK];
    __shared__ __align__(16) u16 Bs[2][BN * BK];

    const int tid = threadIdx.x;
    const int lane = tid & 63;
    const int w = tid >> 6, wr = w >> 1, wc = w & 1;
    const int lr = lane & 15, lq = lane >> 4;
    int bx = blockIdx.x, by = blockIdx.y;
    xcd_swz(bx, by);
    const int m0 = by * BM, n0 = bx * BN;

    const int sr  = tid >> 3;
    const int ss  = tid & 7;
    const int gsl = ss ^ (sr & 7);

    f32x4 acc[MR][NR] = {};

    auto stage = [&](int buf, int kt) {
        #pragma unroll
        for (int ch = 0; ch < CA; ch++)
            gload16(A + (size_t)(m0 + ch * 32 + sr) * K + kt + gsl * 8,
                    &As[buf][ch * 2048 + tid * 8]);
        #pragma unroll
        for (int ch = 0; ch < CB; ch++)
            gload16(Bt + (size_t)(n0 + ch * 32 + sr) * K + kt + gsl * 8,
                    &Bs[buf][ch * 2048 + tid * 8]);
    };

    stage(0, 0);
    int cur = 0;
    for (int t = 0; t < NT; t++) {
        __syncthreads();
        if (t + 1 < NT) stage(cur ^ 1, (t + 1) * BK);
        const u16* as = As[cur]; const u16* bs = Bs[cur];
        #pragma unroll
        for (int ks = 0; ks < 2; ks++) {
            s16x8 af[MR], bfv[NR];
            #pragma unroll
            for (int m = 0; m < MR; m++) {
                int r = wr * (BM / 2) + m * 16 + lr;
                af[m] = *(const s16x8*)(as + r * 64 + (((ks * 4 + lq) ^ (r & 7)) * 8));
            }
            #pragma unroll
            for (int n = 0; n < NR; n++) {
                int r = wc * (BN / 2) + n * 16 + lr;
                bfv[n] = *(const s16x8*)(bs + r * 64 + (((ks * 4 + lq) ^ (r & 7)) * 8));
            }
            #pragma unroll
            for (int m = 0; m < MR; m++)
                #pragma unroll
                for (int n = 0; n < NR; n++)
                    acc[m][n] = __builtin_amdgcn_mfma_f32_16x16x32_bf16(af[m], bfv[n], acc[m][n], 0, 0, 0);
        }
        cur ^= 1;
    }

    #pragma unroll
    for (int m = 0; m < MR; m++) {
        #pragma unroll
        for (int n = 0; n < NR; n++) {
            #pragma unroll
            for (int j = 0; j < 4; j++) {
                int row = m0 + wr * (BM / 2) + m * 16 + lq * 4 + j;
                int col = n0 + wc * (BN / 2) + n * 16 + lr;
                float v = acc[m][n][j];
                if (EPI == 0) {
                    if (col < 512) Obf0[(size_t)row * 512 + col] = f2bf(v);
                    else           Obf1[(size_t)row * 512 + col - 512] = f2bf(v);
                } else {
                    v += bias[col];
                    v = (v >= 0.f) ? v : 0.2f * v;
                    Of[(size_t)row * 256 + col] = v;
                }
            }
        }
    }
}

// ---------------- scores + softmax + m1: per-batch LDS staging ----------------
// 256 WGs, 4 per batch (XCD-swizzled so they share the batch on one XCD).
__global__ __launch_bounds__(256)
void scores_m1_kernel(const u16* __restrict__ a_bf, const u16* __restrict__ bp_bf,
                      const u16* __restrict__ x_bf,
                      const float* __restrict__ b1, const float* __restrict__ W2,
                      const float* __restrict__ b2,
                      const int* __restrict__ region_indices,
                      float* __restrict__ adjw, u16* __restrict__ m1)
{
    __shared__ __align__(16) u16 bp_lds[64 * 512];   // 64 KB
    __shared__ __align__(16) u16 x_lds[64 * 512];    // 64 KB
    __shared__ int ri_lds[64];
    __shared__ int rid_lds[64];

    int L = blockIdx.x;
    int nid = ((L & 7) << 5) + (L >> 3);   // 256 WGs -> contiguous nid per XCD
    const int b = nid >> 2, q = nid & 3;
    const int tid = threadIdx.x, lane = tid & 63, w = tid >> 6;

    #pragma unroll
    for (int it = 0; it < 16; it++) {
        gload16(bp_bf + (size_t)b * 32768 + it * 2048 + tid * 8, bp_lds + it * 2048 + tid * 8);
        gload16(x_bf  + (size_t)b * 32768 + it * 2048 + tid * 8, x_lds  + it * 2048 + tid * 8);
    }
    if (tid < 64) {
        int c = region_indices[tid];
        ri_lds[tid] = c;
        rid_lds[c] = tid >> 3;
    }

    const int d0 = lane * 8;
    float4 b1a = *(const float4*)(b1 + d0), b1b = *(const float4*)(b1 + d0 + 4);
    float4 w2a = *(const float4*)(W2 + d0), w2b = *(const float4*)(W2 + d0 + 4);
    float b1v[8] = { b1a.x, b1a.y, b1a.z, b1a.w, b1b.x, b1b.y, b1b.z, b1b.w };
    float w2v[8] = { w2a.x, w2a.y, w2a.z, w2a.w, w2b.x, w2b.y, w2b.z, w2b.w };
    const float bias2 = b2[0];

    __syncthreads();   // staging + rid tables ready

    for (int rr = 0; rr < 4; rr++) {
        const int i = q * 16 + w * 4 + rr;
        const int bi = b * 64 + i;
        const int r = rid_lds[i];
        int mem[8];
        #pragma unroll
        for (int m = 0; m < 8; m++) mem[m] = ri_lds[r * 8 + m];

        s16x8 a8 = *(const s16x8*)(a_bf + (size_t)bi * 512 + d0);
        float ai[8];
        #pragma unroll
        for (int t = 0; t < 8; t++) ai[t] = bf2f((u16)a8[t]) + b1v[t];

        float p[8];
        #pragma unroll
        for (int m = 0; m < 8; m++) {
            s16x8 bv = *(const s16x8*)(bp_lds + mem[m] * 512 + d0);
            float s = 0.f;
            #pragma unroll
            for (int t = 0; t < 8; t++) {
                float h = ai[t] + bf2f((u16)bv[t]);
                s += fmaxf(h, 0.f) * w2v[t];
            }
            p[m] = s;
        }
        #pragma unroll
        for (int off = 32; off >= 1; off >>= 1)
            #pragma unroll
            for (int m = 0; m < 8; m++) p[m] += __shfl_xor(p[m], off);

        float scmax = -INFINITY;
        #pragma unroll
        for (int m = 0; m < 8; m++) {
            p[m] = (mem[m] == i) ? -INFINITY : p[m] + bias2;
            scmax = fmaxf(scmax, p[m]);
        }
        float esum = 0.f;
        #pragma unroll
        for (int m = 0; m < 8; m++) {
            p[m] = (mem[m] == i) ? 0.f : __expf(p[m] - scmax);
            esum += p[m];
        }
        const float inv = 1.f / esum;

        float accv[8] = {};
        #pragma unroll
        for (int m = 0; m < 8; m++) {
            p[m] *= inv;
            s16x8 xv = *(const s16x8*)(x_lds + mem[m] * 512 + d0);
            #pragma unroll
            for (int t = 0; t < 8; t++) accv[t] += p[m] * bf2f((u16)xv[t]);
        }
        s16x8 o;
        #pragma unroll
        for (int t = 0; t < 8; t++) o[t] = (short)f2bf(accv[t]);
        *(s16x8*)(m1 + (size_t)bi * 512 + d0) = o;
        if (lane < 8) adjw[(size_t)bi * 8 + lane] = p[lane];
    }
}

// ---------------- GEMM2 (x1) + fused m2: batch-aligned BM=64, BN=64 ----------
__global__ __launch_bounds__(256)
void gemm2_m2_kernel(const u16* __restrict__ A, const u16* __restrict__ Bt,
                     const float* __restrict__ bias, const float* __restrict__ xres,
                     const float* __restrict__ adjw, const int* __restrict__ region_indices,
                     u16* __restrict__ m2)
{
    constexpr int K = 512, BK = 64, NT = K / BK;
    __shared__ __align__(16) u16 As[2][64 * 64];
    __shared__ __align__(16) u16 Bs[2][64 * 64];
    __shared__ __align__(16) u16 x1s[64 * 72];   // pad 72 -> member rows on distinct banks
    __shared__ int ri_lds[64];
    __shared__ int rid_lds[64];

    const int tid = threadIdx.x;
    const int lane = tid & 63;
    const int w = tid >> 6, wr = w >> 1, wc = w & 1;
    const int lr = lane & 15, lq = lane >> 4;
    int bx = blockIdx.x, by = blockIdx.y;
    xcd_swz(bx, by);
    const int b = by, n0 = bx * 64;
    const int m0 = b * 64;

    const int sr = tid >> 3, ss = tid & 7;
    const int gsl = ss ^ (sr & 7);

    if (tid < 64) {
        int c = region_indices[tid];
        ri_lds[tid] = c;
        rid_lds[c] = tid >> 3;
    }

    f32x4 acc[2][2] = {};

    auto stage = [&](int buf, int kt) {
        #pragma unroll
        for (int ch = 0; ch < 2; ch++)
            gload16(A + (size_t)(m0 + ch * 32 + sr) * K + kt + gsl * 8,
                    &As[buf][ch * 2048 + tid * 8]);
        #pragma unroll
        for (int ch = 0; ch < 2; ch++)
            gload16(Bt + (size_t)(n0 + ch * 32 + sr) * K + kt + gsl * 8,
                    &Bs[buf][ch * 2048 + tid * 8]);
    };

    stage(0, 0);
    int cur = 0;
    for (int t = 0; t < NT; t++) {
        __syncthreads();
        if (t + 1 < NT) stage(cur ^ 1, (t + 1) * BK);
        const u16* as = As[cur]; const u16* bs = Bs[cur];
        #pragma unroll
        for (int ks = 0; ks < 2; ks++) {
            s16x8 af[2], bfv[2];
            #pragma unroll
            for (int m = 0; m < 2; m++) {
                int r = wr * 32 + m * 16 + lr;
                af[m] = *(const s16x8*)(as + r * 64 + (((ks * 4 + lq) ^ (r & 7)) * 8));
            }
            #pragma unroll
            for (int n = 0; n < 2; n++) {
                int r = wc * 32 + n * 16 + lr;
                bfv[n] = *(const s16x8*)(bs + r * 64 + (((ks * 4 + lq) ^ (r & 7)) * 8));
            }
            #pragma unroll
            for (int m = 0; m < 2; m++)
                #pragma unroll
                for (int n = 0; n < 2; n++)
                    acc[m][n] = __builtin_amdgcn_mfma_f32_16x16x32_bf16(af[m], bfv[n], acc[m][n], 0, 0, 0);
        }
        cur ^= 1;
    }

    // epilogue 1: x1 tile -> LDS (bias + leaky + 0.5 mix with fp32 residual)
    #pragma unroll
    for (int m = 0; m < 2; m++) {
        #pragma unroll
        for (int n = 0; n < 2; n++) {
            #pragma unroll
            for (int j = 0; j < 4; j++) {
                int lrow = wr * 32 + m * 16 + lq * 4 + j;
                int lcol = wc * 32 + n * 16 + lr;
                float v = acc[m][n][j] + bias[n0 + lcol];
                v = (v >= 0.f) ? v : 0.2f * v;
                v = 0.5f * v + 0.5f * xres[(size_t)(m0 + lrow) * 512 + n0 + lcol];
                x1s[lrow * 72 + lcol] = f2bf(v);
            }
        }
    }
    __syncthreads();

    // epilogue 2: m2[i, n0..n0+64) = sum_m adjw[bi,m] * x1[member_m]
    const int i = tid >> 2, cb = tid & 3, c0 = cb * 16;
    const int bi = m0 + i;
    const int r = rid_lds[i];
    float acc2[16] = {};
    #pragma unroll
    for (int m = 0; m < 8; m++) {
        float wm = adjw[(size_t)bi * 8 + m];
        int j = ri_lds[r * 8 + m];
        #pragma unroll
        for (int cc = 0; cc < 2; cc++) {
            s16x8 v = *(const s16x8*)(x1s + j * 72 + c0 + cc * 8);
            #pragma unroll
            for (int t = 0; t < 8; t++) acc2[cc * 8 + t] += wm * bf2f((u16)v[t]);
        }
    }
    #pragma unroll
    for (int cc = 0; cc < 2; cc++) {
        s16x8 o;
        #pragma unroll
        for (int t = 0; t < 8; t++) o[t] = (short)f2bf(acc2[cc * 8 + t]);
        *(s16x8*)(m2 + (size_t)bi * 512 + n0 + c0 + cc * 8) = o;
    }
}

// ---------------- launch ----------------
extern "C" void kernel_launch(void* const* d_in, const int* in_sizes, int n_in,
                              void* d_out, int out_size, void* d_ws, size_t ws_size,
                              hipStream_t stream) {
    const float* x    = (const float*)d_in[0];
    const float* W1   = (const float*)d_in[1];
    const float* b1   = (const float*)d_in[2];
    const float* W2   = (const float*)d_in[3];
    const float* b2   = (const float*)d_in[4];
    const float* Wg1  = (const float*)d_in[5];
    const float* bg1  = (const float*)d_in[6];
    const float* Wg2  = (const float*)d_in[7];
    const float* bg2  = (const float*)d_in[8];
    const int* region_indices = (const int*)d_in[9];
    float* out = (float*)d_out;

    char* ws = (char*)d_ws;
    const size_t MB = 1024 * 1024;
    u16*   x_bf  = (u16*)(ws);                        // 4 MB
    u16*   W1t   = (u16*)(ws + 4 * MB);               // 1 MB   [1024][512]
    u16*   Wg1t  = (u16*)(ws + 5 * MB);               // 0.5 MB [512][512]
    u16*   Wg2t  = (u16*)(ws + 5 * MB + 512 * 1024);  // 0.25MB [256][512]
    u16*   a_bf  = (u16*)(ws + 6 * MB);               // 4 MB
    u16*   bp_bf = (u16*)(ws + 10 * MB);              // 4 MB
    u16*   m1_bf = (u16*)(ws + 14 * MB);              // 4 MB
    u16*   m2_bf = (u16*)(ws + 18 * MB);              // 4 MB
    float* adjw  = (float*)(ws + 22 * MB);            // 128 KB

    prep_kernel<<<1920, 256, 0, stream>>>(x, x_bf, W1, W1t, Wg1, Wg1t, Wg2, Wg2t);

    // a | bp = x @ [W1a|W1b]  (M=4096, N=1024, K=512), 512 WGs, 2/CU
    mfma_gemm<128, 64, 0><<<dim3(16, 32), 256, 0, stream>>>(
        x_bf, W1t, a_bf, bp_bf, nullptr, nullptr);

    scores_m1_kernel<<<256, 256, 0, stream>>>(a_bf, bp_bf, x_bf, b1, W2, b2,
                                              region_indices, adjw, m1_bf);

    // x1 (LDS-only) + m2 = adj @ x1  (M=4096, N=512), 512 WGs batch-aligned
    gemm2_m2_kernel<<<dim3(8, 64), 256, 0, stream>>>(
        m1_bf, Wg1t, bg1, x, adjw, region_indices, m2_bf);

    // out = leaky(m2@Wg2+bg2)  (N=256, fp32), 256 WGs
    mfma_gemm<64, 64, 2><<<dim3(4, 64), 256, 0, stream>>>(
        m2_bf, Wg2t, nullptr, nullptr, bg2, out);
}

// Round 5
// 119.226 us; speedup vs baseline: 2.3692x; 1.0088x over previous
//
#include <hip/hip_runtime.h>
#include <math.h>

#define B_   64
#define C_   64
#define D_   512
#define O_   256
#define G_   8
#define M_   4096

typedef __attribute__((ext_vector_type(8))) short s16x8;
typedef __attribute__((ext_vector_type(4))) float f32x4;
typedef unsigned short u16;
typedef unsigned int   u32;

__device__ __forceinline__ float bf2f(u16 u) { return __uint_as_float(((u32)u) << 16); }
__device__ __forceinline__ u16 f2bf(float f) {
    u32 u = __float_as_uint(f);
    return (u16)((u + 0x7FFFu + ((u >> 16) & 1u)) >> 16);
}
__device__ __forceinline__ void gload16(const void* g, void* l) {
    __builtin_amdgcn_global_load_lds((const __attribute__((address_space(1))) u32*)g,
                                     (__attribute__((address_space(3))) u32*)l, 16, 0, 0);
}
// bijective XCD swizzle: nwg multiple of 8; nx a power of 2
__device__ __forceinline__ void xcd_swz(int& bx, int& by) {
    int nx = (int)gridDim.x;
    int L = bx + by * nx;
    int nwg = nx * (int)gridDim.y;
    int nid = (L & 7) * (nwg >> 3) + (L >> 3);
    bx = nid & (nx - 1);
    by = nid / nx;
}

// ---------------- prep: x->bf16, W transposes -> bf16 B^T ----------------
__global__ __launch_bounds__(256)
void prep_kernel(const float* __restrict__ x, u16* __restrict__ x_bf,
                 const float* __restrict__ W1, u16* __restrict__ W1t,
                 const float* __restrict__ Wg1, u16* __restrict__ Wg1t,
                 const float* __restrict__ Wg2, u16* __restrict__ Wg2t)
{
    __shared__ float tile[32][33];
    const int bx = blockIdx.x, tid = threadIdx.x;
    if (bx < 1024) {
        size_t i = ((size_t)bx * 256 + tid) * 8;
        const float4* p = (const float4*)(x + i);
        float4 v0 = p[0], v1 = p[1];
        s16x8 o;
        o[0] = (short)f2bf(v0.x); o[1] = (short)f2bf(v0.y);
        o[2] = (short)f2bf(v0.z); o[3] = (short)f2bf(v0.w);
        o[4] = (short)f2bf(v1.x); o[5] = (short)f2bf(v1.y);
        o[6] = (short)f2bf(v1.z); o[7] = (short)f2bf(v1.w);
        *(s16x8*)(x_bf + i) = o;
        return;
    }
    const float* src; u16* dst; int k0, n0, nsrc, obase;
    if (bx < 1536) {
        int idx = bx - 1024, h = idx >> 8, t = idx & 255;
        src = W1 + (size_t)h * 512 * 512; dst = W1t; obase = h * 512;
        k0 = (t >> 4) * 32; n0 = (t & 15) * 32; nsrc = 512;
    } else if (bx < 1792) {
        int t = bx - 1536;
        src = Wg1; dst = Wg1t; obase = 0;
        k0 = (t >> 4) * 32; n0 = (t & 15) * 32; nsrc = 512;
    } else {
        int t = bx - 1792;
        src = Wg2; dst = Wg2t; obase = 0;
        k0 = (t >> 3) * 32; n0 = (t & 7) * 32; nsrc = 256;
    }
    int tx = tid & 31, ty = tid >> 5;
    #pragma unroll
    for (int j = 0; j < 4; j++)
        tile[ty + j * 8][tx] = src[(size_t)(k0 + ty + j * 8) * nsrc + n0 + tx];
    __syncthreads();
    #pragma unroll
    for (int j = 0; j < 4; j++)
        dst[(size_t)(obase + n0 + ty + j * 8) * 512 + k0 + tx] = f2bf(tile[tx][ty + j * 8]);
}

// ---------------- GEMM1: 128x128 tile, 512 threads (8 waves 4Mx2N) ----------
// a | bpart = x @ [W1a|W1b]; bf16 out split at col 512.
__global__ __launch_bounds__(512)
void gemm1_kernel(const u16* __restrict__ A, const u16* __restrict__ Bt,
                  u16* __restrict__ Obf0, u16* __restrict__ Obf1)
{
    constexpr int K = 512, BK = 64, NT = K / BK;
    __shared__ __align__(16) u16 As[2][128 * 64];
    __shared__ __align__(16) u16 Bs[2][128 * 64];

    const int tid = threadIdx.x;
    const int lane = tid & 63;
    const int w = tid >> 6;               // 0..7
    const int wr = w >> 1, wc = w & 1;    // 4 x 2
    const int lr = lane & 15, lq = lane >> 4;
    int bx = blockIdx.x, by = blockIdx.y;
    xcd_swz(bx, by);
    const int m0 = by * 128, n0 = bx * 128;

    const int sr = tid >> 3;              // 0..63 (row within 64-row chunk)
    const int ss = tid & 7;
    const int gsl = ss ^ (sr & 7);

    f32x4 acc[2][4] = {};                 // MR=2, NR=4

    auto stage = [&](int buf, int kt) {
        #pragma unroll
        for (int ch = 0; ch < 2; ch++)
            gload16(A + (size_t)(m0 + ch * 64 + sr) * K + kt + gsl * 8,
                    &As[buf][ch * 4096 + tid * 8]);
        #pragma unroll
        for (int ch = 0; ch < 2; ch++)
            gload16(Bt + (size_t)(n0 + ch * 64 + sr) * K + kt + gsl * 8,
                    &Bs[buf][ch * 4096 + tid * 8]);
    };

    stage(0, 0);
    int cur = 0;
    for (int t = 0; t < NT; t++) {
        __syncthreads();
        if (t + 1 < NT) stage(cur ^ 1, (t + 1) * BK);
        const u16* as = As[cur]; const u16* bs = Bs[cur];
        #pragma unroll
        for (int ks = 0; ks < 2; ks++) {
            s16x8 af[2], bfv[4];
            #pragma unroll
            for (int m = 0; m < 2; m++) {
                int r = wr * 32 + m * 16 + lr;
                af[m] = *(const s16x8*)(as + r * 64 + (((ks * 4 + lq) ^ (r & 7)) * 8));
            }
            #pragma unroll
            for (int n = 0; n < 4; n++) {
                int r = wc * 64 + n * 16 + lr;
                bfv[n] = *(const s16x8*)(bs + r * 64 + (((ks * 4 + lq) ^ (r & 7)) * 8));
            }
            #pragma unroll
            for (int m = 0; m < 2; m++)
                #pragma unroll
                for (int n = 0; n < 4; n++)
                    acc[m][n] = __builtin_amdgcn_mfma_f32_16x16x32_bf16(af[m], bfv[n], acc[m][n], 0, 0, 0);
        }
        cur ^= 1;
    }

    #pragma unroll
    for (int m = 0; m < 2; m++) {
        #pragma unroll
        for (int n = 0; n < 4; n++) {
            #pragma unroll
            for (int j = 0; j < 4; j++) {
                int row = m0 + wr * 32 + m * 16 + lq * 4 + j;
                int col = n0 + wc * 64 + n * 16 + lr;
                float v = acc[m][n][j];
                if (col < 512) Obf0[(size_t)row * 512 + col] = f2bf(v);
                else           Obf1[(size_t)row * 512 + col - 512] = f2bf(v);
            }
        }
    }
}

// ---------------- scores + softmax + m1: bp staged, x direct ----------------
__global__ __launch_bounds__(256)
void scores_m1_kernel(const u16* __restrict__ a_bf, const u16* __restrict__ bp_bf,
                      const u16* __restrict__ x_bf,
                      const float* __restrict__ b1, const float* __restrict__ W2,
                      const float* __restrict__ b2,
                      const int* __restrict__ region_indices,
                      float* __restrict__ adjw, u16* __restrict__ m1)
{
    __shared__ __align__(16) u16 bp_lds[64 * 512];   // 64 KB
    __shared__ int ri_lds[64];
    __shared__ int rid_lds[64];

    int L = blockIdx.x;
    int nid = ((L & 7) << 5) + (L >> 3);
    const int b = nid >> 2, q = nid & 3;
    const int tid = threadIdx.x, lane = tid & 63, w = tid >> 6;

    #pragma unroll
    for (int it = 0; it < 16; it++)
        gload16(bp_bf + (size_t)b * 32768 + it * 2048 + tid * 8, bp_lds + it * 2048 + tid * 8);
    if (tid < 64) {
        int c = region_indices[tid];
        ri_lds[tid] = c;
        rid_lds[c] = tid >> 3;
    }

    const int d0 = lane * 8;
    float4 b1a = *(const float4*)(b1 + d0), b1b = *(const float4*)(b1 + d0 + 4);
    float4 w2a = *(const float4*)(W2 + d0), w2b = *(const float4*)(W2 + d0 + 4);
    float b1v[8] = { b1a.x, b1a.y, b1a.z, b1a.w, b1b.x, b1b.y, b1b.z, b1b.w };
    float w2v[8] = { w2a.x, w2a.y, w2a.z, w2a.w, w2b.x, w2b.y, w2b.z, w2b.w };
    const float bias2 = b2[0];

    __syncthreads();

    for (int rr = 0; rr < 4; rr++) {
        const int i = q * 16 + w * 4 + rr;
        const int bi = b * 64 + i;
        const int r = rid_lds[i];
        int mem[8];
        #pragma unroll
        for (int m = 0; m < 8; m++) mem[m] = ri_lds[r * 8 + m];

        s16x8 a8 = *(const s16x8*)(a_bf + (size_t)bi * 512 + d0);
        float ai[8];
        #pragma unroll
        for (int t = 0; t < 8; t++) ai[t] = bf2f((u16)a8[t]) + b1v[t];

        float p[8];
        #pragma unroll
        for (int m = 0; m < 8; m++) {
            s16x8 bv = *(const s16x8*)(bp_lds + mem[m] * 512 + d0);
            float s = 0.f;
            #pragma unroll
            for (int t = 0; t < 8; t++) {
                float h = ai[t] + bf2f((u16)bv[t]);
                s += fmaxf(h, 0.f) * w2v[t];
            }
            p[m] = s;
        }
        #pragma unroll
        for (int off = 32; off >= 1; off >>= 1)
            #pragma unroll
            for (int m = 0; m < 8; m++) p[m] += __shfl_xor(p[m], off);

        float scmax = -INFINITY;
        #pragma unroll
        for (int m = 0; m < 8; m++) {
            p[m] = (mem[m] == i) ? -INFINITY : p[m] + bias2;
            scmax = fmaxf(scmax, p[m]);
        }
        float esum = 0.f;
        #pragma unroll
        for (int m = 0; m < 8; m++) {
            p[m] = (mem[m] == i) ? 0.f : __expf(p[m] - scmax);
            esum += p[m];
        }
        const float inv = 1.f / esum;

        float accv[8] = {};
        #pragma unroll
        for (int m = 0; m < 8; m++) {
            p[m] *= inv;
            s16x8 xv = *(const s16x8*)(x_bf + ((size_t)(b * 64 + mem[m])) * 512 + d0);
            #pragma unroll
            for (int t = 0; t < 8; t++) accv[t] += p[m] * bf2f((u16)xv[t]);
        }
        s16x8 o;
        #pragma unroll
        for (int t = 0; t < 8; t++) o[t] = (short)f2bf(accv[t]);
        *(s16x8*)(m1 + (size_t)bi * 512 + d0) = o;
        if (lane < 8) adjw[(size_t)bi * 8 + lane] = p[lane];
    }
}

// ---------------- GEMM2 (x1) + fused m2: BM=64 (batch), BN=128, 512 thr -----
__global__ __launch_bounds__(512)
void gemm2_m2_kernel(const u16* __restrict__ A, const u16* __restrict__ Bt,
                     const float* __restrict__ bias, const float* __restrict__ xres,
                     const float* __restrict__ adjw, const int* __restrict__ region_indices,
                     u16* __restrict__ m2)
{
    constexpr int K = 512, BK = 64, NT = K / BK;
    __shared__ __align__(16) u16 As[2][64 * 64];
    __shared__ __align__(16) u16 Bs[2][128 * 64];
    __shared__ __align__(16) u16 x1s[64 * 136];
    __shared__ int ri_lds[64];
    __shared__ int rid_lds[64];

    const int tid = threadIdx.x;
    const int lane = tid & 63;
    const int w = tid >> 6;               // 0..7
    const int wr = w >> 2, wc = w & 3;    // 2 x 4
    const int lr = lane & 15, lq = lane >> 4;
    int bx = blockIdx.x, by = blockIdx.y;
    xcd_swz(bx, by);
    const int b = by, n0 = bx * 128, m0 = b * 64;

    const int sr = tid >> 3, ss = tid & 7;
    const int gsl = ss ^ (sr & 7);

    if (tid < 64) {
        int c = region_indices[tid];
        ri_lds[tid] = c;
        rid_lds[c] = tid >> 3;
    }

    f32x4 acc[2][2] = {};                 // MR=2, NR=2

    auto stage = [&](int buf, int kt) {
        gload16(A + (size_t)(m0 + sr) * K + kt + gsl * 8, &As[buf][tid * 8]);
        #pragma unroll
        for (int ch = 0; ch < 2; ch++)
            gload16(Bt + (size_t)(n0 + ch * 64 + sr) * K + kt + gsl * 8,
                    &Bs[buf][ch * 4096 + tid * 8]);
    };

    stage(0, 0);
    int cur = 0;
    for (int t = 0; t < NT; t++) {
        __syncthreads();
        if (t + 1 < NT) stage(cur ^ 1, (t + 1) * BK);
        const u16* as = As[cur]; const u16* bs = Bs[cur];
        #pragma unroll
        for (int ks = 0; ks < 2; ks++) {
            s16x8 af[2], bfv[2];
            #pragma unroll
            for (int m = 0; m < 2; m++) {
                int r = wr * 32 + m * 16 + lr;
                af[m] = *(const s16x8*)(as + r * 64 + (((ks * 4 + lq) ^ (r & 7)) * 8));
            }
            #pragma unroll
            for (int n = 0; n < 2; n++) {
                int r = wc * 32 + n * 16 + lr;
                bfv[n] = *(const s16x8*)(bs + r * 64 + (((ks * 4 + lq) ^ (r & 7)) * 8));
            }
            #pragma unroll
            for (int m = 0; m < 2; m++)
                #pragma unroll
                for (int n = 0; n < 2; n++)
                    acc[m][n] = __builtin_amdgcn_mfma_f32_16x16x32_bf16(af[m], bfv[n], acc[m][n], 0, 0, 0);
        }
        cur ^= 1;
    }

    // epilogue 1: x1 tile -> LDS (bias + leaky + 0.5 mix with fp32 residual)
    #pragma unroll
    for (int m = 0; m < 2; m++) {
        #pragma unroll
        for (int n = 0; n < 2; n++) {
            #pragma unroll
            for (int j = 0; j < 4; j++) {
                int lrow = wr * 32 + m * 16 + lq * 4 + j;
                int lcol = wc * 32 + n * 16 + lr;
                float v = acc[m][n][j] + bias[n0 + lcol];
                v = (v >= 0.f) ? v : 0.2f * v;
                v = 0.5f * v + 0.5f * xres[(size_t)(m0 + lrow) * 512 + n0 + lcol];
                x1s[lrow * 136 + lcol] = f2bf(v);
            }
        }
    }
    __syncthreads();

    // epilogue 2: m2[i, n0..n0+128) = sum_m adjw[bi,m] * x1[member_m]
    const int i = tid >> 3, cb = tid & 7, c0 = cb * 16;
    const int bi = m0 + i;
    const int r = rid_lds[i];
    float acc2[16] = {};
    #pragma unroll
    for (int m = 0; m < 8; m++) {
        float wm = adjw[(size_t)bi * 8 + m];
        int j = ri_lds[r * 8 + m];
        #pragma unroll
        for (int cc = 0; cc < 2; cc++) {
            s16x8 v = *(const s16x8*)(x1s + j * 136 + c0 + cc * 8);
            #pragma unroll
            for (int t = 0; t < 8; t++) acc2[cc * 8 + t] += wm * bf2f((u16)v[t]);
        }
    }
    #pragma unroll
    for (int cc = 0; cc < 2; cc++) {
        s16x8 o;
        #pragma unroll
        for (int t = 0; t < 8; t++) o[t] = (short)f2bf(acc2[cc * 8 + t]);
        *(s16x8*)(m2 + (size_t)bi * 512 + n0 + c0 + cc * 8) = o;
    }
}

// ---------------- GEMM3: out = leaky(m2@Wg2+bg2), 64x64, fp32 out ----------
__global__ __launch_bounds__(256)
void gemm3_kernel(const u16* __restrict__ A, const u16* __restrict__ Bt,
                  const float* __restrict__ bias, float* __restrict__ Of)
{
    constexpr int K = 512, BK = 64, NT = K / BK;
    __shared__ __align__(16) u16 As[2][64 * 64];
    __shared__ __align__(16) u16 Bs[2][64 * 64];

    const int tid = threadIdx.x;
    const int lane = tid & 63;
    const int w = tid >> 6, wr = w >> 1, wc = w & 1;
    const int lr = lane & 15, lq = lane >> 4;
    int bx = blockIdx.x, by = blockIdx.y;
    xcd_swz(bx, by);
    const int m0 = by * 64, n0 = bx * 64;

    const int sr = tid >> 3, ss = tid & 7;
    const int gsl = ss ^ (sr & 7);

    f32x4 acc[2][2] = {};

    auto stage = [&](int buf, int kt) {
        #pragma unroll
        for (int ch = 0; ch < 2; ch++)
            gload16(A + (size_t)(m0 + ch * 32 + sr) * K + kt + gsl * 8,
                    &As[buf][ch * 2048 + tid * 8]);
        #pragma unroll
        for (int ch = 0; ch < 2; ch++)
            gload16(Bt + (size_t)(n0 + ch * 32 + sr) * K + kt + gsl * 8,
                    &Bs[buf][ch * 2048 + tid * 8]);
    };

    stage(0, 0);
    int cur = 0;
    for (int t = 0; t < NT; t++) {
        __syncthreads();
        if (t + 1 < NT) stage(cur ^ 1, (t + 1) * BK);
        const u16* as = As[cur]; const u16* bs = Bs[cur];
        #pragma unroll
        for (int ks = 0; ks < 2; ks++) {
            s16x8 af[2], bfv[2];
            #pragma unroll
            for (int m = 0; m < 2; m++) {
                int r = wr * 32 + m * 16 + lr;
                af[m] = *(const s16x8*)(as + r * 64 + (((ks * 4 + lq) ^ (r & 7)) * 8));
            }
            #pragma unroll
            for (int n = 0; n < 2; n++) {
                int r = wc * 32 + n * 16 + lr;
                bfv[n] = *(const s16x8*)(bs + r * 64 + (((ks * 4 + lq) ^ (r & 7)) * 8));
            }
            #pragma unroll
            for (int m = 0; m < 2; m++)
                #pragma unroll
                for (int n = 0; n < 2; n++)
                    acc[m][n] = __builtin_amdgcn_mfma_f32_16x16x32_bf16(af[m], bfv[n], acc[m][n], 0, 0, 0);
        }
        cur ^= 1;
    }

    #pragma unroll
    for (int m = 0; m < 2; m++) {
        #pragma unroll
        for (int n = 0; n < 2; n++) {
            #pragma unroll
            for (int j = 0; j < 4; j++) {
                int row = m0 + wr * 32 + m * 16 + lq * 4 + j;
                int col = n0 + wc * 32 + n * 16 + lr;
                float v = acc[m][n][j] + bias[col];
                v = (v >= 0.f) ? v : 0.2f * v;
                Of[(size_t)row * 256 + col] = v;
            }
        }
    }
}

// ---------------- launch ----------------
extern "C" void kernel_launch(void* const* d_in, const int* in_sizes, int n_in,
                              void* d_out, int out_size, void* d_ws, size_t ws_size,
                              hipStream_t stream) {
    const float* x    = (const float*)d_in[0];
    const float* W1   = (const float*)d_in[1];
    const float* b1   = (const float*)d_in[2];
    const float* W2   = (const float*)d_in[3];
    const float* b2   = (const float*)d_in[4];
    const float* Wg1  = (const float*)d_in[5];
    const float* bg1  = (const float*)d_in[6];
    const float* Wg2  = (const float*)d_in[7];
    const float* bg2  = (const float*)d_in[8];
    const int* region_indices = (const int*)d_in[9];
    float* out = (float*)d_out;

    char* ws = (char*)d_ws;
    const size_t MB = 1024 * 1024;
    u16*   x_bf  = (u16*)(ws);                        // 4 MB
    u16*   W1t   = (u16*)(ws + 4 * MB);               // 1 MB   [1024][512]
    u16*   Wg1t  = (u16*)(ws + 5 * MB);               // 0.5 MB [512][512]
    u16*   Wg2t  = (u16*)(ws + 5 * MB + 512 * 1024);  // 0.25MB [256][512]
    u16*   a_bf  = (u16*)(ws + 6 * MB);               // 4 MB
    u16*   bp_bf = (u16*)(ws + 10 * MB);              // 4 MB
    u16*   m1_bf = (u16*)(ws + 14 * MB);              // 4 MB
    u16*   m2_bf = (u16*)(ws + 18 * MB);              // 4 MB
    float* adjw  = (float*)(ws + 22 * MB);            // 128 KB

    prep_kernel<<<1920, 256, 0, stream>>>(x, x_bf, W1, W1t, Wg1, Wg1t, Wg2, Wg2t);

    // a | bp = x @ [W1a|W1b]  (M=4096, N=1024, K=512), 256 WGs x 512 thr
    gemm1_kernel<<<dim3(8, 32), 512, 0, stream>>>(x_bf, W1t, a_bf, bp_bf);

    scores_m1_kernel<<<256, 256, 0, stream>>>(a_bf, bp_bf, x_bf, b1, W2, b2,
                                              region_indices, adjw, m1_bf);

    // x1 (LDS-only) + m2 = adj @ x1  (M=4096, N=512), 256 WGs x 512 thr
    gemm2_m2_kernel<<<dim3(4, 64), 512, 0, stream>>>(
        m1_bf, Wg1t, bg1, x, adjw, region_indices, m2_bf);

    // out = leaky(m2@Wg2+bg2)  (N=256, fp32), 256 WGs
    gemm3_kernel<<<dim3(4, 64), 256, 0, stream>>>(m2_bf, Wg2t, bg2, out);
}